// Round 6
// baseline (474.356 us; speedup 1.0000x reference)
//
#include <hip/hip_runtime.h>
#include <hip/hip_bf16.h>

#define NEG_SLOPE 0.2f

// ---------------------------------------------------------------------------
// GAT 2-layer, N=100k, E=3.2M (+self-loops handled analytically per node).
//
// R6: R5 structure kept (256-node bucket sort, 4x 64-node window blocks for
// aggregation), but the window edge loops are rewritten with 4-edge ILP:
// R5 counters showed ~650 cyc exposed latency/iteration (VALUBusy 4.8%,
// HBM 4.5%, occ 42% -> pure latency-bound, one dependent gather chain per
// iteration). Now: 4 independent pair loads -> 4 predicated gathers in
// flight -> straight-line compute. Sentinel 0xFFFFFFFF pads the tail
// (decodes to window 511, never matches).
//
// Layer 1 collapses because IN==1 (h1 = x*W1 is rank-1):
//   logit_src[n,h]=x[n]*S1[h], logit_dst[n,h]=x[n]*D1[h],
//   out1[n,h,c]=W1[h,c]*t1[n,h]+b1. No softmax max-subtraction needed
//   (|logit| <~ 30, exp safe in fp32; verified R2-R5 absmax 9.8e-4).
//
// ws layout (4B units):
//   [0..15]      consts S1[4],D1[4]
//   [16..527]    gcnt[512]    (zeroed)
//   [528..1039]  gbase[512]
//   [1040..1551] gcursor[512]
//   [+N]         als2
//   [+N]         ald2
//   [+8N]        h2
//   [+E]         pairs (packed src | local_dst<<17)
// Guards: N <= 131072 (17-bit src, <=512 buckets). Fallback: R2 atomic path.
// ---------------------------------------------------------------------------

__global__ void prep_consts(const float* __restrict__ W1,
                            const float* __restrict__ as1,
                            const float* __restrict__ ad1,
                            float* __restrict__ consts) {
    int t = threadIdx.x;
    if (t >= 8) return;
    int h = t & 3;
    const float* a = (t < 4) ? as1 : ad1;
    float s = 0.f;
    #pragma unroll
    for (int c = 0; c < 8; ++c)
        s += W1[h * 8 + c] * a[h * 8 + c];
    consts[t] = s;
}

__global__ void bucket_hist(const int* __restrict__ ei, int* __restrict__ gcnt, int E) {
    __shared__ int cnt[512];
    int t = threadIdx.x;
    cnt[t] = 0; cnt[t + 256] = 0;
    __syncthreads();
    int stride = gridDim.x * 256;
    for (int e = blockIdx.x * 256 + t; e < E; e += stride)
        atomicAdd(&cnt[ei[E + e] >> 8], 1);
    __syncthreads();
    for (int i = t; i < 512; i += 256) {
        int c = cnt[i];
        if (c) atomicAdd(&gcnt[i], c);
    }
}

// single block, 512 threads: exclusive scan of bucket counts
__global__ void scan_init(const int* __restrict__ gcnt,
                          int* __restrict__ gbase, int* __restrict__ gcursor) {
    __shared__ int buf[512];
    int t = threadIdx.x;
    int orig = gcnt[t];
    buf[t] = orig;
    __syncthreads();
    for (int o = 1; o < 512; o <<= 1) {
        int add = (t >= o) ? buf[t - o] : 0;
        __syncthreads();
        buf[t] += add;
        __syncthreads();
    }
    int base = buf[t] - orig;
    gbase[t] = base;
    gcursor[t] = base;
}

__global__ void bucket_scatter(const int* __restrict__ ei, int* __restrict__ gcursor,
                               unsigned int* __restrict__ pairs, int E) {
    __shared__ int cnt[512];
    __shared__ int basel[512];
    int t = threadIdx.x;
    int chunk = (E + gridDim.x - 1) / gridDim.x;
    int lo = blockIdx.x * chunk;
    int hi = min(E, lo + chunk);
    cnt[t] = 0; cnt[t + 256] = 0;
    __syncthreads();
    for (int e = lo + t; e < hi; e += 256)
        atomicAdd(&cnt[ei[E + e] >> 8], 1);
    __syncthreads();
    for (int i = t; i < 512; i += 256) {
        int c = cnt[i];
        basel[i] = c ? atomicAdd(&gcursor[i], c) : 0;
        cnt[i] = 0;
    }
    __syncthreads();
    for (int e = lo + t; e < hi; e += 256) {
        int s = ei[e];
        int d = ei[E + e];
        int bk = d >> 8;
        int loc = atomicAdd(&cnt[bk], 1);
        pairs[basel[bk] + loc] = (unsigned)s | ((unsigned)(d & 255) << 17);
    }
}

// Layer-1 aggregation + epilogue + W2 transform + layer-2 logits.
// One block per (bucket, 64-node window): blockIdx = bk*4 + w. 4-edge ILP.
__global__ void l1_win(const float* __restrict__ x,
                       const int* __restrict__ gbase, const int* __restrict__ gcnt,
                       const unsigned int* __restrict__ pairs,
                       const float* __restrict__ consts,
                       const float* __restrict__ W1, const float* __restrict__ b1,
                       const float* __restrict__ W2,
                       const float* __restrict__ as2, const float* __restrict__ ad2,
                       float* __restrict__ h2, float* __restrict__ als2,
                       float* __restrict__ ald2, int N) {
    __shared__ float st[64 * 9];   // window rows: [0..3]=s1[h], [4..7]=t1[h]
    __shared__ float xl[64];
    int t = threadIdx.x;
    int bk = blockIdx.x >> 2;
    int w  = blockIdx.x & 3;
    int node0 = (bk << 8) + (w << 6);
    int nw = min(64, N - node0);
    if (t < 64) {
        #pragma unroll
        for (int j = 0; j < 9; ++j) st[t * 9 + j] = 0.f;
        if (t < nw) xl[t] = x[node0 + t];
    }
    float S[4], D[4];
    #pragma unroll
    for (int h = 0; h < 4; ++h) { S[h] = consts[h]; D[h] = consts[4 + h]; }
    __syncthreads();
    int b = gbase[bk];
    int hi = b + gcnt[bk];
    for (int i = b + t * 4; i < hi; i += 1024) {
        unsigned p[4];
        int srcv[4], ldv[4];
        bool m[4];
        #pragma unroll
        for (int k = 0; k < 4; ++k) {
            int idx = i + k;
            p[k] = (idx < hi) ? pairs[idx] : 0xFFFFFFFFu;
        }
        #pragma unroll
        for (int k = 0; k < 4; ++k) {
            ldv[k] = (int)(p[k] >> 17);
            srcv[k] = (int)(p[k] & 131071u);
            m[k] = (ldv[k] >> 6) == w;
        }
        float xs[4];
        #pragma unroll
        for (int k = 0; k < 4; ++k)
            xs[k] = m[k] ? x[srcv[k]] : 0.f;     // 4 predicated gathers in flight
        #pragma unroll
        for (int k = 0; k < 4; ++k) {
            if (!m[k]) continue;
            int ld = ldv[k] & 63;
            float xd = xl[ld];
            float* row = &st[ld * 9];
            #pragma unroll
            for (int h = 0; h < 4; ++h) {
                float v = xs[k] * S[h] + xd * D[h];
                v = (v > 0.f) ? v : NEG_SLOPE * v;
                float ww = __expf(v);
                atomicAdd(&row[h], ww);
                atomicAdd(&row[4 + h], ww * xs[k]);
            }
        }
    }
    __syncthreads();
    if (t < nw) {
        int n = node0 + t;
        float xn = xl[t];
        float o[8];
        #pragma unroll
        for (int c = 0; c < 8; ++c) o[c] = 0.f;
        #pragma unroll
        for (int h = 0; h < 4; ++h) {
            float v = xn * (S[h] + D[h]);           // self-loop term
            v = (v > 0.f) ? v : NEG_SLOPE * v;
            float ww = __expf(v);
            float s1 = st[t * 9 + h] + ww;
            float tt = (st[t * 9 + 4 + h] + ww * xn) / s1;
            #pragma unroll
            for (int c = 0; c < 8; ++c) {
                float r = fmaxf(tt * W1[h * 8 + c] + b1[h * 8 + c], 0.f);
                #pragma unroll
                for (int c2 = 0; c2 < 8; ++c2) o[c2] += r * W2[(h * 8 + c) * 8 + c2];
            }
        }
        float as = 0.f, ad = 0.f;
        #pragma unroll
        for (int c = 0; c < 8; ++c) { as += o[c] * as2[c]; ad += o[c] * ad2[c]; }
        float4* hv = (float4*)&h2[(size_t)n * 8];
        hv[0] = make_float4(o[0], o[1], o[2], o[3]);
        hv[1] = make_float4(o[4], o[5], o[6], o[7]);
        als2[n] = as;
        ald2[n] = ad;
    }
}

// Layer-2 aggregation + output epilogue, per (bucket, window). 4-edge ILP.
__global__ void l2_win(const int* __restrict__ gbase, const int* __restrict__ gcnt,
                       const unsigned int* __restrict__ pairs,
                       const float* __restrict__ als2, const float* __restrict__ ald2,
                       const float* __restrict__ h2, const float* __restrict__ b2,
                       float* __restrict__ out, int N) {
    __shared__ float sa[64 * 9];   // window rows: [0]=s2, [1..8]=acc
    __shared__ float all[64], adl[64];
    int t = threadIdx.x;
    int bk = blockIdx.x >> 2;
    int w  = blockIdx.x & 3;
    int node0 = (bk << 8) + (w << 6);
    int nw = min(64, N - node0);
    if (t < 64) {
        #pragma unroll
        for (int j = 0; j < 9; ++j) sa[t * 9 + j] = 0.f;
        if (t < nw) { all[t] = als2[node0 + t]; adl[t] = ald2[node0 + t]; }
    }
    __syncthreads();
    int b = gbase[bk];
    int hi = b + gcnt[bk];
    for (int i = b + t * 4; i < hi; i += 1024) {
        unsigned p[4];
        int srcv[4], ldv[4];
        bool m[4];
        #pragma unroll
        for (int k = 0; k < 4; ++k) {
            int idx = i + k;
            p[k] = (idx < hi) ? pairs[idx] : 0xFFFFFFFFu;
        }
        #pragma unroll
        for (int k = 0; k < 4; ++k) {
            ldv[k] = (int)(p[k] >> 17);
            srcv[k] = (int)(p[k] & 131071u);
            m[k] = (ldv[k] >> 6) == w;
        }
        float al[4];
        float4 ha[4], hb[4];
        #pragma unroll
        for (int k = 0; k < 4; ++k) {
            if (m[k]) {
                al[k] = als2[srcv[k]];
                const float4* hv = (const float4*)&h2[(size_t)srcv[k] * 8];
                ha[k] = hv[0];
                hb[k] = hv[1];
            } else {
                al[k] = 0.f;
                ha[k] = make_float4(0.f, 0.f, 0.f, 0.f);
                hb[k] = make_float4(0.f, 0.f, 0.f, 0.f);
            }
        }
        #pragma unroll
        for (int k = 0; k < 4; ++k) {
            if (!m[k]) continue;
            int ld = ldv[k] & 63;
            float v = al[k] + adl[ld];
            v = (v > 0.f) ? v : NEG_SLOPE * v;
            float ww = __expf(v);
            float* row = &sa[ld * 9];
            atomicAdd(&row[0], ww);
            atomicAdd(&row[1], ww * ha[k].x); atomicAdd(&row[2], ww * ha[k].y);
            atomicAdd(&row[3], ww * ha[k].z); atomicAdd(&row[4], ww * ha[k].w);
            atomicAdd(&row[5], ww * hb[k].x); atomicAdd(&row[6], ww * hb[k].y);
            atomicAdd(&row[7], ww * hb[k].z); atomicAdd(&row[8], ww * hb[k].w);
        }
    }
    __syncthreads();
    if (t < nw) {
        int n = node0 + t;
        float v = all[t] + adl[t];               // self-loop
        v = (v > 0.f) ? v : NEG_SLOPE * v;
        float ww = __expf(v);
        const float4* hv = (const float4*)&h2[(size_t)n * 8];
        float4 ha0 = hv[0], hb0 = hv[1];
        float s2 = sa[t * 9] + ww;
        float inv = 1.f / s2;
        float4* ov = (float4*)&out[(size_t)n * 8];
        ov[0] = make_float4((sa[t * 9 + 1] + ww * ha0.x) * inv + b2[0],
                            (sa[t * 9 + 2] + ww * ha0.y) * inv + b2[1],
                            (sa[t * 9 + 3] + ww * ha0.z) * inv + b2[2],
                            (sa[t * 9 + 4] + ww * ha0.w) * inv + b2[3]);
        ov[1] = make_float4((sa[t * 9 + 5] + ww * hb0.x) * inv + b2[4],
                            (sa[t * 9 + 6] + ww * hb0.y) * inv + b2[5],
                            (sa[t * 9 + 7] + ww * hb0.z) * inv + b2[6],
                            (sa[t * 9 + 8] + ww * hb0.w) * inv + b2[7]);
    }
}

// ---------------- fallback path (R2, atomic-based; known-correct) ----------------

__global__ void edge_pass1(const int* __restrict__ ei, const float* __restrict__ x,
                           const float* __restrict__ consts,
                           float* __restrict__ s1, float* __restrict__ t1, int E, int N) {
    int e = blockIdx.x * blockDim.x + threadIdx.x;
    if (e >= E + N) return;
    int src, dst;
    if (e < E) { src = ei[e]; dst = ei[E + e]; }
    else       { src = dst = e - E; }
    float xs = x[src], xd = x[dst];
    #pragma unroll
    for (int h = 0; h < 4; ++h) {
        float v = xs * consts[h] + xd * consts[4 + h];
        v = (v > 0.f) ? v : NEG_SLOPE * v;
        float w = __expf(v);
        atomicAdd(&s1[dst * 4 + h], w);
        atomicAdd(&t1[dst * 4 + h], w * xs);
    }
}

__global__ void node_mid(const float* __restrict__ s1, const float* __restrict__ t1,
                         const float* __restrict__ W1, const float* __restrict__ b1,
                         const float* __restrict__ W2,
                         const float* __restrict__ as2, const float* __restrict__ ad2,
                         float* __restrict__ h2, float* __restrict__ als2,
                         float* __restrict__ ald2, int N) {
    int n = blockIdx.x * blockDim.x + threadIdx.x;
    if (n >= N) return;
    float o[8];
    #pragma unroll
    for (int c = 0; c < 8; ++c) o[c] = 0.f;
    #pragma unroll
    for (int h = 0; h < 4; ++h) {
        float t = t1[n * 4 + h] / s1[n * 4 + h];
        #pragma unroll
        for (int c = 0; c < 8; ++c) {
            float r = fmaxf(t * W1[h * 8 + c] + b1[h * 8 + c], 0.f);
            #pragma unroll
            for (int c2 = 0; c2 < 8; ++c2) o[c2] += r * W2[(h * 8 + c) * 8 + c2];
        }
    }
    float as = 0.f, ad = 0.f;
    #pragma unroll
    for (int c = 0; c < 8; ++c) { h2[n * 8 + c] = o[c]; as += o[c] * as2[c]; ad += o[c] * ad2[c]; }
    als2[n] = as; ald2[n] = ad;
}

__global__ void edge_pass2(const int* __restrict__ ei, const float* __restrict__ als2,
                           const float* __restrict__ ald2, const float* __restrict__ h2,
                           float* __restrict__ s2, float* __restrict__ acc2, int E, int N) {
    int e = blockIdx.x * blockDim.x + threadIdx.x;
    if (e >= E + N) return;
    int src, dst;
    if (e < E) { src = ei[e]; dst = ei[E + e]; }
    else       { src = dst = e - E; }
    float v = als2[src] + ald2[dst];
    v = (v > 0.f) ? v : NEG_SLOPE * v;
    float w = __expf(v);
    atomicAdd(&s2[dst], w);
    const float4* hs = (const float4*)&h2[src * 8];
    float4 a = hs[0], bq = hs[1];
    float* acc = &acc2[dst * 8];
    atomicAdd(&acc[0], w * a.x);  atomicAdd(&acc[1], w * a.y);
    atomicAdd(&acc[2], w * a.z);  atomicAdd(&acc[3], w * a.w);
    atomicAdd(&acc[4], w * bq.x); atomicAdd(&acc[5], w * bq.y);
    atomicAdd(&acc[6], w * bq.z); atomicAdd(&acc[7], w * bq.w);
}

__global__ void node_out(const float* __restrict__ s2, const float* __restrict__ acc2,
                         const float* __restrict__ b2, float* __restrict__ out, int N) {
    int i = blockIdx.x * blockDim.x + threadIdx.x;
    if (i >= N * 8) return;
    out[i] = acc2[i] / s2[i >> 3] + b2[i & 7];
}

// ---------------------------------------------------------------------------

extern "C" void kernel_launch(void* const* d_in, const int* in_sizes, int n_in,
                              void* d_out, int out_size, void* d_ws, size_t ws_size,
                              hipStream_t stream) {
    const float* x   = (const float*)d_in[0];
    const int*   ei  = (const int*)d_in[1];
    const float* W1  = (const float*)d_in[2];
    const float* as1 = (const float*)d_in[3];
    const float* ad1 = (const float*)d_in[4];
    const float* b1  = (const float*)d_in[5];
    const float* W2  = (const float*)d_in[6];
    const float* as2 = (const float*)d_in[7];
    const float* ad2 = (const float*)d_in[8];
    const float* b2  = (const float*)d_in[9];
    float* out = (float*)d_out;

    const int N = in_sizes[0];          // 100000
    const int E = in_sizes[1] / 2;      // 3200000
    const int NB = (N + 255) >> 8;      // 391 buckets of 256 nodes

    float* ws = (float*)d_ws;
    size_t need = (size_t)(1552 + 10 * (size_t)N + (size_t)E) * sizeof(float);

    if (N <= 131072 && ws_size >= need) {
        float*    consts  = ws;                         // 16
        int*      gcnt    = (int*)(ws + 16);            // 512
        int*      gbase   = gcnt + 512;                 // 512
        int*      gcursor = gbase + 512;                // 512
        float*    als2    = ws + 1552;                  // N
        float*    ald2    = als2 + N;                   // N
        float*    h2      = ald2 + N;                   // 8N
        unsigned* pairs   = (unsigned*)(h2 + 8 * (size_t)N);  // E

        hipMemsetAsync(gcnt, 0, 512 * sizeof(int), stream);
        prep_consts<<<1, 64, 0, stream>>>(W1, as1, ad1, consts);
        bucket_hist<<<512, 256, 0, stream>>>(ei, gcnt, E);
        scan_init<<<1, 512, 0, stream>>>(gcnt, gbase, gcursor);
        bucket_scatter<<<512, 256, 0, stream>>>(ei, gcursor, pairs, E);
        l1_win<<<NB * 4, 256, 0, stream>>>(x, gbase, gcnt, pairs, consts,
                                           W1, b1, W2, as2, ad2, h2, als2, ald2, N);
        l2_win<<<NB * 4, 256, 0, stream>>>(gbase, gcnt, pairs, als2, ald2, h2, b2, out, N);
    } else {
        // fallback: R2 atomic path (10.8 MB ws, known-correct)
        float* consts = ws;
        float* s1   = ws + 16;
        float* t1   = s1 + 4 * (size_t)N;
        float* h2   = t1 + 4 * (size_t)N;
        float* als2 = h2 + 8 * (size_t)N;
        float* ald2 = als2 + (size_t)N;
        float* s2   = ald2 + (size_t)N;
        float* acc2 = s2 + (size_t)N;

        hipMemsetAsync(ws, 0, (16 + 8 * (size_t)N) * sizeof(float), stream);
        hipMemsetAsync(s2, 0, 9 * (size_t)N * sizeof(float), stream);
        prep_consts<<<1, 64, 0, stream>>>(W1, as1, ad1, consts);
        int total = E + N;
        edge_pass1<<<(total + 255) / 256, 256, 0, stream>>>(ei, x, consts, s1, t1, E, N);
        node_mid<<<(N + 255) / 256, 256, 0, stream>>>(s1, t1, W1, b1, W2, as2, ad2, h2, als2, ald2, N);
        edge_pass2<<<(total + 255) / 256, 256, 0, stream>>>(ei, als2, ald2, h2, s2, acc2, E, N);
        node_out<<<(N * 8 + 255) / 256, 256, 0, stream>>>(s2, acc2, b2, out, N);
    }
}